// Round 1
// baseline (408.602 us; speedup 1.0000x reference)
//
#include <hip/hip_runtime.h>
#include <hip/hip_bf16.h>
#include <cstdint>

#define BATCH 4
#define SEQ   2048
#define DIN   1024
#define DOUT  1024
#define SCALE 0.03125f   // 1/sqrt(1024)

typedef unsigned short u16;
typedef float  f32x4  __attribute__((ext_vector_type(4)));
typedef __bf16 bf16x8 __attribute__((ext_vector_type(8)));

__device__ __forceinline__ u16 f2bf(float f) {
    unsigned u = __float_as_uint(f);
    unsigned r = 0x7fffu + ((u >> 16) & 1u);
    return (u16)((u + r) >> 16);
}

__device__ __forceinline__ f32x4 mfma16(bf16x8 a, bf16x8 b, f32x4 c) {
    return __builtin_amdgcn_mfma_f32_16x16x32_bf16(a, b, c, 0, 0, 0);
}

// ---------------- fp32 -> bf16 conversion (8 elems/thread) ----------------
__global__ __launch_bounds__(256) void cvt_bf16(const float* __restrict__ in,
                                                u16* __restrict__ out) {
    size_t i = ((size_t)blockIdx.x * 256 + threadIdx.x) * 8;
    f32x4 a = *(const f32x4*)(in + i);
    f32x4 b = *(const f32x4*)(in + i + 4);
    uint4 o;
    o.x = (unsigned)f2bf(a[0]) | ((unsigned)f2bf(a[1]) << 16);
    o.y = (unsigned)f2bf(a[2]) | ((unsigned)f2bf(a[3]) << 16);
    o.z = (unsigned)f2bf(b[0]) | ((unsigned)f2bf(b[1]) << 16);
    o.w = (unsigned)f2bf(b[2]) | ((unsigned)f2bf(b[3]) << 16);
    *(uint4*)(out + i) = o;
}

// ---------------- QKV GEMM: C[M,N] = X[M,K] * W[N,K]^T, bf16 out ----------
#define BM 128
#define BN 128
#define BK 32

__global__ __launch_bounds__(256) void qkv_gemm(const u16* __restrict__ xb,
                                                const u16* __restrict__ wb,
                                                u16* __restrict__ qkv) {
    __shared__ __align__(16) u16 As[BM * BK];
    __shared__ __align__(16) u16 Bs[BN * BK];
    const int mt = blockIdx.x, nt = blockIdx.y, wsel = blockIdx.z;
    const u16* Wp = wb + (size_t)wsel * DOUT * DIN;
    u16* Op = qkv + (size_t)wsel * (size_t)(BATCH * SEQ) * DOUT;
    const int tid = threadIdx.x;
    const int lane = tid & 63, wv = tid >> 6;
    const int wr = (wv >> 1) * 64, wc = (wv & 1) * 64;
    const int l15 = lane & 15, l4 = lane >> 4;
    const int m0 = mt * BM, n0 = nt * BN;
    f32x4 acc[4][4] = {};

    for (int k0 = 0; k0 < DIN; k0 += BK) {
        __syncthreads();
#pragma unroll
        for (int i = 0; i < 2; i++) {
            int e = (tid + i * 256) * 8;
            int r = e >> 5, c = e & 31;
            uint4 av = *(const uint4*)&xb[(size_t)(m0 + r) * DIN + k0 + c];
            uint4 bv = *(const uint4*)&Wp[(size_t)(n0 + r) * DIN + k0 + c];
            int byo = r * 64 + ((c * 2) ^ ((r & 3) << 4));
            *(uint4*)((char*)As + byo) = av;
            *(uint4*)((char*)Bs + byo) = bv;
        }
        __syncthreads();
        bf16x8 af[4], bfr[4];
#pragma unroll
        for (int mi = 0; mi < 4; mi++) {
            int r = wr + mi * 16 + l15;
            af[mi] = *(const bf16x8*)((const char*)As + r * 64 + ((l4 * 16) ^ ((r & 3) << 4)));
        }
#pragma unroll
        for (int ni = 0; ni < 4; ni++) {
            int r = wc + ni * 16 + l15;
            bfr[ni] = *(const bf16x8*)((const char*)Bs + r * 64 + ((l4 * 16) ^ ((r & 3) << 4)));
        }
#pragma unroll
        for (int mi = 0; mi < 4; mi++)
#pragma unroll
            for (int ni = 0; ni < 4; ni++)
                acc[mi][ni] = mfma16(af[mi], bfr[ni], acc[mi][ni]);
    }
#pragma unroll
    for (int mi = 0; mi < 4; mi++)
#pragma unroll
        for (int rr = 0; rr < 4; rr++) {
            int grow = m0 + wr + mi * 16 + l4 * 4 + rr;
#pragma unroll
            for (int ni = 0; ni < 4; ni++) {
                int gcol = n0 + wc + ni * 16 + l15;
                Op[(size_t)grow * DOUT + gcol] = f2bf(acc[mi][ni][rr]);
            }
        }
}

// ---------------- V transpose: v[b][s][d] -> vt[b][d][s] -------------------
__global__ __launch_bounds__(256) void vtrans(const u16* __restrict__ v,
                                              u16* __restrict__ vt) {
    __shared__ __align__(16) u16 t[64][80];
    const int s0 = blockIdx.x * 64, d0 = blockIdx.y * 64;
    const size_t bo = (size_t)blockIdx.z * SEQ * DOUT;
    const int tid = threadIdx.x;
#pragma unroll
    for (int i = 0; i < 2; i++) {
        int e = (tid + i * 256) * 8;
        int r = e >> 6, c = e & 63;
        *(uint4*)&t[r][c] = *(const uint4*)&v[bo + (size_t)(s0 + r) * DOUT + d0 + c];
    }
    __syncthreads();
#pragma unroll
    for (int i = 0; i < 2; i++) {
        int e = (tid + i * 256) * 8;
        int rd = e >> 6, cs = e & 63;
        u16 tmp[8];
#pragma unroll
        for (int j = 0; j < 8; j++) tmp[j] = t[cs + j][rd];
        uint4 o;
        o.x = (unsigned)tmp[0] | ((unsigned)tmp[1] << 16);
        o.y = (unsigned)tmp[2] | ((unsigned)tmp[3] << 16);
        o.z = (unsigned)tmp[4] | ((unsigned)tmp[5] << 16);
        o.w = (unsigned)tmp[6] | ((unsigned)tmp[7] << 16);
        *(uint4*)&vt[bo + (size_t)(d0 + rd) * SEQ + s0 + cs] = o;
    }
}

// ---------------- causal flash attention -----------------------------------
#define QT 32
#define KT 64
#define DC 128

__global__ __launch_bounds__(512) void attn(const u16* __restrict__ qg,
                                            const u16* __restrict__ kg,
                                            const u16* __restrict__ vtg,
                                            float* __restrict__ outg) {
    __shared__ __align__(16) u16  Qs[QT * DIN];   // [32][1024] swizzled
    __shared__ __align__(16) u16  Ks[KT * DC];    // [64][128]  swizzled
    __shared__ __align__(16) u16  Vs[DC * KT];    // [128][64]  swizzled (d-major)
    __shared__ __align__(16) float Sls[QT * KT];  // [32][64]
    __shared__ __align__(16) u16  Ps[QT * KT];    // [32][64]  swizzled
    __shared__ float mS[QT], lS[QT], rS[QT];

    const int qt = blockIdx.x, b = blockIdx.y;
    const int q0 = qt * QT;
    const size_t bo = (size_t)b * SEQ * DOUT;
    const int tid = threadIdx.x, lane = tid & 63, wv = tid >> 6;
    const int l15 = lane & 15, l4 = lane >> 4;

    // stage Q tile (resident for whole block)
#pragma unroll
    for (int i = 0; i < 8; i++) {
        int e = (tid + i * 512) * 8;
        int r = e >> 10, c = e & 1023;
        uint4 v = *(const uint4*)&qg[bo + (size_t)(q0 + r) * DOUT + c];
        *(uint4*)((char*)Qs + r * 2048 + ((c * 2) ^ ((r & 15) << 4))) = v;
    }
    if (tid < QT) { mS[tid] = -__builtin_inff(); lS[tid] = 0.f; }
    f32x4 o[2][8] = {};
    const int nkt = ((q0 + QT - 1) >> 6) + 1;
    const int sr = (wv >> 2) * 16, sc = (wv & 3) * 16;
    __syncthreads();

    for (int kt = 0; kt < nkt; kt++) {
        const int k0 = kt * KT;
        f32x4 sacc = {0.f, 0.f, 0.f, 0.f};
        // ---- QK^T over d-chunks ----
        for (int dc = 0; dc < DIN / DC; dc++) {
#pragma unroll
            for (int i = 0; i < 2; i++) {
                int e = (tid + i * 512) * 8;
                int r = e >> 7, c = e & 127;
                uint4 v = *(const uint4*)&kg[bo + (size_t)(k0 + r) * DOUT + dc * DC + c];
                *(uint4*)((char*)Ks + r * 256 + ((c * 2) ^ ((r & 15) << 4))) = v;
            }
            __syncthreads();
#pragma unroll
            for (int kk = 0; kk < 4; kk++) {
                int qr = sr + l15;
                int colb = dc * 256 + (kk * 32 + l4 * 8) * 2;
                bf16x8 aq = *(const bf16x8*)((const char*)Qs + qr * 2048 + (colb ^ ((qr & 15) << 4)));
                int kr = sc + l15;
                int colk = (kk * 32 + l4 * 8) * 2;
                bf16x8 bk = *(const bf16x8*)((const char*)Ks + kr * 256 + (colk ^ ((kr & 15) << 4)));
                sacc = mfma16(aq, bk, sacc);
            }
            __syncthreads();
        }
        // ---- causal mask + scale -> Sls ----
#pragma unroll
        for (int rr = 0; rr < 4; rr++) {
            int row = sr + l4 * 4 + rr;
            int col = sc + l15;
            bool valid = (k0 + col) <= (q0 + row);
            Sls[row * KT + col] = valid ? sacc[rr] * SCALE : -__builtin_inff();
        }
        __syncthreads();
        // ---- online softmax: 16 threads per row ----
        {
            int row = tid >> 4, g = tid & 15;
            f32x4 sv = *(const f32x4*)&Sls[row * KT + g * 4];
            float tmax = fmaxf(fmaxf(sv[0], sv[1]), fmaxf(sv[2], sv[3]));
#pragma unroll
            for (int m = 8; m >= 1; m >>= 1) tmax = fmaxf(tmax, __shfl_xor(tmax, m, 16));
            float mold = mS[row];
            float mnew = fmaxf(mold, tmax);
            float rsc = __expf(mold - mnew);
            f32x4 p;
            p[0] = __expf(sv[0] - mnew); p[1] = __expf(sv[1] - mnew);
            p[2] = __expf(sv[2] - mnew); p[3] = __expf(sv[3] - mnew);
            float psum = p[0] + p[1] + p[2] + p[3];
#pragma unroll
            for (int m = 8; m >= 1; m >>= 1) psum += __shfl_xor(psum, m, 16);
            uint2 pw;
            pw.x = (unsigned)f2bf(p[0]) | ((unsigned)f2bf(p[1]) << 16);
            pw.y = (unsigned)f2bf(p[2]) | ((unsigned)f2bf(p[3]) << 16);
            *(uint2*)((char*)Ps + row * 128 + ((g * 8) ^ ((row & 7) << 4))) = pw;
            if (g == 0) { mS[row] = mnew; lS[row] = lS[row] * rsc + psum; rS[row] = rsc; }
        }
        __syncthreads();
        // ---- rescale O ----
#pragma unroll
        for (int mi = 0; mi < 2; mi++)
#pragma unroll
            for (int rr = 0; rr < 4; rr++) {
                float rsv = rS[mi * 16 + l4 * 4 + rr];
#pragma unroll
                for (int dc = 0; dc < 8; dc++) o[mi][dc][rr] *= rsv;
            }
        // ---- PV over d-chunks ----
        for (int dc = 0; dc < 8; dc++) {
#pragma unroll
            for (int i = 0; i < 2; i++) {
                int e = (tid + i * 512) * 8;
                int r = e >> 6, c = e & 63;
                uint4 v = *(const uint4*)&vtg[bo + (size_t)(dc * DC + r) * SEQ + k0 + c];
                *(uint4*)((char*)Vs + r * 128 + ((c * 2) ^ ((r & 7) << 4))) = v;
            }
            __syncthreads();
#pragma unroll
            for (int mi = 0; mi < 2; mi++)
#pragma unroll
                for (int kk = 0; kk < 2; kk++) {
                    int prow = mi * 16 + l15;
                    int pcolb = (kk * 32 + l4 * 8) * 2;
                    bf16x8 ap = *(const bf16x8*)((const char*)Ps + prow * 128 + (pcolb ^ ((prow & 7) << 4)));
                    int vrow = wv * 16 + l15;
                    int vcolb = (kk * 32 + l4 * 8) * 2;
                    bf16x8 bv = *(const bf16x8*)((const char*)Vs + vrow * 128 + (vcolb ^ ((vrow & 7) << 4)));
                    o[mi][dc] = mfma16(ap, bv, o[mi][dc]);
                }
            __syncthreads();
        }
    }
    // ---- epilogue: divide by softmax denom, write fp32 ----
#pragma unroll
    for (int mi = 0; mi < 2; mi++)
#pragma unroll
        for (int rr = 0; rr < 4; rr++) {
            int row = mi * 16 + l4 * 4 + rr;
            float inv = 1.0f / lS[row];
#pragma unroll
            for (int dc = 0; dc < 8; dc++) {
                int d = dc * DC + wv * 16 + l15;
                outg[bo + (size_t)(q0 + row) * DOUT + d] = o[mi][dc][rr] * inv;
            }
        }
}

extern "C" void kernel_launch(void* const* d_in, const int* in_sizes, int n_in,
                              void* d_out, int out_size, void* d_ws, size_t ws_size,
                              hipStream_t stream) {
    const float* x  = (const float*)d_in[0];
    const float* wq = (const float*)d_in[1];
    const float* wk = (const float*)d_in[2];
    const float* wv = (const float*)d_in[3];
    float* out = (float*)d_out;

    const size_t NX = (size_t)BATCH * SEQ * DIN;  // 8M elems
    const size_t NWT = (size_t)DOUT * DIN;        // 1M elems
    u16* xb  = (u16*)d_ws;
    u16* wb  = xb + NX;
    u16* qkv = wb + 3 * NWT;
    u16* vt  = qkv + 3 * NX;

    cvt_bf16<<<NX / 8 / 256, 256, 0, stream>>>(x, xb);
    cvt_bf16<<<NWT / 8 / 256, 256, 0, stream>>>(wq, wb);
    cvt_bf16<<<NWT / 8 / 256, 256, 0, stream>>>(wk, wb + NWT);
    cvt_bf16<<<NWT / 8 / 256, 256, 0, stream>>>(wv, wb + 2 * NWT);

    qkv_gemm<<<dim3(64, 8, 3), 256, 0, stream>>>(xb, wb, qkv);

    vtrans<<<dim3(SEQ / 64, DOUT / 64, BATCH), 256, 0, stream>>>(qkv + 2 * NX, vt);

    attn<<<dim3(SEQ / QT, BATCH), 512, 0, stream>>>(qkv, qkv + NX, vt, out);
}

// Round 2
// 211.299 us; speedup vs baseline: 1.9338x; 1.9338x over previous
//
#include <hip/hip_runtime.h>
#include <hip/hip_bf16.h>
#include <cstdint>

#define BATCH 4
#define SEQ   2048
#define DIN   1024
#define DOUT  1024
#define SCALE 0.03125f   // 1/sqrt(1024)

typedef unsigned short u16;
typedef float  f32x4  __attribute__((ext_vector_type(4)));
typedef __bf16 bf16x8 __attribute__((ext_vector_type(8)));

__device__ __forceinline__ u16 f2bf(float f) {
    unsigned u = __float_as_uint(f);
    unsigned r = 0x7fffu + ((u >> 16) & 1u);
    return (u16)((u + r) >> 16);
}

__device__ __forceinline__ f32x4 mfma16(bf16x8 a, bf16x8 b, f32x4 c) {
    return __builtin_amdgcn_mfma_f32_16x16x32_bf16(a, b, c, 0, 0, 0);
}

// async global->LDS, 16B per lane, wave-uniform LDS base
__device__ __forceinline__ void gl_lds16(const u16* g, u16* l) {
    __builtin_amdgcn_global_load_lds(
        (const __attribute__((address_space(1))) unsigned int*)g,
        (__attribute__((address_space(3))) unsigned int*)l, 16, 0, 0);
}

// ---------------- fp32 -> bf16 conversion (8 elems/thread) ----------------
__global__ __launch_bounds__(256) void cvt_bf16(const float* __restrict__ in,
                                                u16* __restrict__ out) {
    size_t i = ((size_t)blockIdx.x * 256 + threadIdx.x) * 8;
    f32x4 a = *(const f32x4*)(in + i);
    f32x4 b = *(const f32x4*)(in + i + 4);
    uint4 o;
    o.x = (unsigned)f2bf(a[0]) | ((unsigned)f2bf(a[1]) << 16);
    o.y = (unsigned)f2bf(a[2]) | ((unsigned)f2bf(a[3]) << 16);
    o.z = (unsigned)f2bf(b[0]) | ((unsigned)f2bf(b[1]) << 16);
    o.w = (unsigned)f2bf(b[2]) | ((unsigned)f2bf(b[3]) << 16);
    *(uint4*)(out + i) = o;
}

// ---------------- shared GEMM pieces: 128x128 tile, BK=64, 4 waves --------
// stage 128x64 u16 tile: 4 iters x 256 threads x 16B via global_load_lds
__device__ __forceinline__ void stage_tile(const u16* __restrict__ g, int ldg,
                                           u16* lds, int tid) {
    const int wv = tid >> 6;
#pragma unroll
    for (int i = 0; i < 4; i++) {
        int e = (i * 256 + tid) * 8;
        int r = e >> 6, c = e & 63;
        gl_lds16(g + (size_t)r * ldg + c, lds + (size_t)(i * 256 + wv * 64) * 8);
    }
}

__device__ __forceinline__ void kstep(const u16* As, const u16* Bs,
                                      int wr, int wc, int l15, int l4,
                                      f32x4 acc[4][4]) {
#pragma unroll
    for (int kk = 0; kk < 2; kk++) {
        bf16x8 af[4], bfr[4];
#pragma unroll
        for (int mi = 0; mi < 4; mi++)
            af[mi] = *(const bf16x8*)&As[(wr + mi * 16 + l15) * 64 + kk * 32 + l4 * 8];
#pragma unroll
        for (int ni = 0; ni < 4; ni++)
            bfr[ni] = *(const bf16x8*)&Bs[(wc + ni * 16 + l15) * 64 + kk * 32 + l4 * 8];
#pragma unroll
        for (int mi = 0; mi < 4; mi++)
#pragma unroll
            for (int ni = 0; ni < 4; ni++)
                acc[mi][ni] = mfma16(af[mi], bfr[ni], acc[mi][ni]);
    }
}

// ---------------- QKV GEMM: C[8192,1024] = X * W^T, bf16 out ---------------
__global__ __launch_bounds__(256) void qkv_gemm(const u16* __restrict__ xb,
                                                const u16* __restrict__ wb,
                                                u16* __restrict__ qkv) {
    __shared__ __align__(16) u16 As[128 * 64];
    __shared__ __align__(16) u16 Bs[128 * 64];
    const int mt = blockIdx.x, nt = blockIdx.y, wsel = blockIdx.z;
    const u16* Wp = wb + (size_t)wsel * DOUT * DIN;
    u16* Op = qkv + (size_t)wsel * (size_t)(BATCH * SEQ) * DOUT;
    const int tid = threadIdx.x, lane = tid & 63, wv = tid >> 6;
    const int wr = (wv >> 1) * 64, wc = (wv & 1) * 64;
    const int l15 = lane & 15, l4 = lane >> 4;
    const int m0 = mt * 128, n0 = nt * 128;
    f32x4 acc[4][4] = {};

    for (int k0 = 0; k0 < DIN; k0 += 64) {
        __syncthreads();
        stage_tile(xb + (size_t)m0 * DIN + k0, DIN, As, tid);
        stage_tile(Wp + (size_t)n0 * DIN + k0, DIN, Bs, tid);
        __syncthreads();
        kstep(As, Bs, wr, wc, l15, l4, acc);
    }
#pragma unroll
    for (int mi = 0; mi < 4; mi++)
#pragma unroll
        for (int rr = 0; rr < 4; rr++) {
            int grow = m0 + wr + mi * 16 + l4 * 4 + rr;
#pragma unroll
            for (int ni = 0; ni < 4; ni++) {
                int gcol = n0 + wc + ni * 16 + l15;
                Op[(size_t)grow * DOUT + gcol] = f2bf(acc[mi][ni][rr]);
            }
        }
}

// ---------------- V transpose: v[b][s][d] -> vt[b][d][s] -------------------
__global__ __launch_bounds__(256) void vtrans(const u16* __restrict__ v,
                                              u16* __restrict__ vt) {
    __shared__ __align__(16) u16 t[64][80];
    const int s0 = blockIdx.x * 64, d0 = blockIdx.y * 64;
    const size_t bo = (size_t)blockIdx.z * SEQ * DOUT;
    const int tid = threadIdx.x;
#pragma unroll
    for (int i = 0; i < 2; i++) {
        int e = (tid + i * 256) * 8;
        int r = e >> 6, c = e & 63;
        *(uint4*)&t[r][c] = *(const uint4*)&v[bo + (size_t)(s0 + r) * DOUT + d0 + c];
    }
    __syncthreads();
#pragma unroll
    for (int i = 0; i < 2; i++) {
        int e = (tid + i * 256) * 8;
        int rd = e >> 6, cs = e & 63;
        u16 tmp[8];
#pragma unroll
        for (int j = 0; j < 8; j++) tmp[j] = t[cs + j][rd];
        uint4 o;
        o.x = (unsigned)tmp[0] | ((unsigned)tmp[1] << 16);
        o.y = (unsigned)tmp[2] | ((unsigned)tmp[3] << 16);
        o.z = (unsigned)tmp[4] | ((unsigned)tmp[5] << 16);
        o.w = (unsigned)tmp[6] | ((unsigned)tmp[7] << 16);
        *(uint4*)&vt[(size_t)blockIdx.z * DOUT * SEQ + (size_t)(d0 + rd) * SEQ + s0 + cs] = o;
    }
}

// ---------------- QK^T: S[b][q][k] (bf16, scaled+masked), causal skip ------
__global__ __launch_bounds__(256) void qk_gemm(const u16* __restrict__ qg,
                                               const u16* __restrict__ kg,
                                               u16* __restrict__ sg) {
    const int mt = blockIdx.x, nt = blockIdx.y, b = blockIdx.z;
    if (nt > mt) return;  // above diagonal: never read downstream
    __shared__ __align__(16) u16 As[128 * 64];
    __shared__ __align__(16) u16 Bs[128 * 64];
    const size_t bo = (size_t)b * SEQ * DOUT;
    const size_t so = (size_t)b * SEQ * SEQ;
    const int tid = threadIdx.x, lane = tid & 63, wv = tid >> 6;
    const int wr = (wv >> 1) * 64, wc = (wv & 1) * 64;
    const int l15 = lane & 15, l4 = lane >> 4;
    const int m0 = mt * 128, n0 = nt * 128;
    f32x4 acc[4][4] = {};

    for (int k0 = 0; k0 < DIN; k0 += 64) {
        __syncthreads();
        stage_tile(qg + bo + (size_t)m0 * DOUT + k0, DOUT, As, tid);
        stage_tile(kg + bo + (size_t)n0 * DOUT + k0, DOUT, Bs, tid);
        __syncthreads();
        kstep(As, Bs, wr, wc, l15, l4, acc);
    }
#pragma unroll
    for (int mi = 0; mi < 4; mi++)
#pragma unroll
        for (int rr = 0; rr < 4; rr++) {
            int q = m0 + wr + mi * 16 + l4 * 4 + rr;
#pragma unroll
            for (int ni = 0; ni < 4; ni++) {
                int kcol = n0 + wc + ni * 16 + l15;
                u16 val = (kcol <= q) ? f2bf(acc[mi][ni][rr] * SCALE) : (u16)0xFF80;
                sg[so + (size_t)q * SEQ + kcol] = val;
            }
        }
}

// ---------------- row softmax in place: one wave per row -------------------
__global__ __launch_bounds__(256) void softmax_rows(u16* __restrict__ sg) {
    const int row = blockIdx.x * 4 + (threadIdx.x >> 6);  // 0..8191
    const int lane = threadIdx.x & 63;
    const int b = row >> 11, q = row & 2047;
    u16* srow = sg + (size_t)b * SEQ * SEQ + (size_t)q * SEQ;
    const int kend = ((q >> 7) + 1) << 7;  // columns valid for this q-tile
    float v[4][8];
    float m = -__builtin_inff();
#pragma unroll
    for (int c = 0; c < 4; c++) {
        int k = c * 512 + lane * 8;
        if (k < kend) {
            uint4 x = *(const uint4*)&srow[k];
            unsigned w0 = x.x, w1 = x.y, w2 = x.z, w3 = x.w;
            v[c][0] = __uint_as_float(w0 << 16); v[c][1] = __uint_as_float(w0 & 0xffff0000u);
            v[c][2] = __uint_as_float(w1 << 16); v[c][3] = __uint_as_float(w1 & 0xffff0000u);
            v[c][4] = __uint_as_float(w2 << 16); v[c][5] = __uint_as_float(w2 & 0xffff0000u);
            v[c][6] = __uint_as_float(w3 << 16); v[c][7] = __uint_as_float(w3 & 0xffff0000u);
        } else {
#pragma unroll
            for (int j = 0; j < 8; j++) v[c][j] = -__builtin_inff();
        }
#pragma unroll
        for (int j = 0; j < 8; j++) m = fmaxf(m, v[c][j]);
    }
#pragma unroll
    for (int off = 32; off >= 1; off >>= 1) m = fmaxf(m, __shfl_xor(m, off));
    float s = 0.f;
#pragma unroll
    for (int c = 0; c < 4; c++)
#pragma unroll
        for (int j = 0; j < 8; j++) { v[c][j] = __expf(v[c][j] - m); s += v[c][j]; }
#pragma unroll
    for (int off = 32; off >= 1; off >>= 1) s += __shfl_xor(s, off);
    float inv = 1.f / s;
#pragma unroll
    for (int c = 0; c < 4; c++) {
        int k = c * 512 + lane * 8;
        if (k < kend) {
            uint4 o;
            o.x = (unsigned)f2bf(v[c][0] * inv) | ((unsigned)f2bf(v[c][1] * inv) << 16);
            o.y = (unsigned)f2bf(v[c][2] * inv) | ((unsigned)f2bf(v[c][3] * inv) << 16);
            o.z = (unsigned)f2bf(v[c][4] * inv) | ((unsigned)f2bf(v[c][5] * inv) << 16);
            o.w = (unsigned)f2bf(v[c][6] * inv) | ((unsigned)f2bf(v[c][7] * inv) << 16);
            *(uint4*)&srow[k] = o;
        }
    }
}

// ---------------- PV: O[b][q][d] = P * V, fp32 out, causal K-bound ---------
__global__ __launch_bounds__(256) void pv_gemm(const u16* __restrict__ pg,
                                               const u16* __restrict__ vtg,
                                               float* __restrict__ og) {
    __shared__ __align__(16) u16 As[128 * 64];
    __shared__ __align__(16) u16 Bs[128 * 64];
    const int mt = blockIdx.x, nt = blockIdx.y, b = blockIdx.z;
    const size_t so = (size_t)b * SEQ * SEQ;
    const size_t vo = (size_t)b * DOUT * SEQ;
    const size_t oo = (size_t)b * SEQ * DOUT;
    const int tid = threadIdx.x, lane = tid & 63, wv = tid >> 6;
    const int wr = (wv >> 1) * 64, wc = (wv & 1) * 64;
    const int l15 = lane & 15, l4 = lane >> 4;
    const int m0 = mt * 128, n0 = nt * 128;
    const int kend = (mt + 1) * 128;
    f32x4 acc[4][4] = {};

    for (int k0 = 0; k0 < kend; k0 += 64) {
        __syncthreads();
        stage_tile(pg + so + (size_t)m0 * SEQ + k0, SEQ, As, tid);
        stage_tile(vtg + vo + (size_t)n0 * SEQ + k0, SEQ, Bs, tid);
        __syncthreads();
        kstep(As, Bs, wr, wc, l15, l4, acc);
    }
#pragma unroll
    for (int mi = 0; mi < 4; mi++)
#pragma unroll
        for (int rr = 0; rr < 4; rr++) {
            int q = m0 + wr + mi * 16 + l4 * 4 + rr;
#pragma unroll
            for (int ni = 0; ni < 4; ni++) {
                int d = n0 + wc + ni * 16 + l15;
                og[oo + (size_t)q * DOUT + d] = acc[mi][ni][rr];
            }
        }
}

extern "C" void kernel_launch(void* const* d_in, const int* in_sizes, int n_in,
                              void* d_out, int out_size, void* d_ws, size_t ws_size,
                              hipStream_t stream) {
    const float* x  = (const float*)d_in[0];
    const float* wq = (const float*)d_in[1];
    const float* wk = (const float*)d_in[2];
    const float* wv = (const float*)d_in[3];
    float* out = (float*)d_out;

    const size_t NX  = (size_t)BATCH * SEQ * DIN;  // 8M elems
    const size_t NWT = (size_t)DOUT * DIN;         // 1M elems
    u16* xb  = (u16*)d_ws;            // 16 MB
    u16* wb  = xb + NX;               // 6 MB
    u16* qkv = wb + 3 * NWT;          // 48 MB (q,k,v)
    u16* vt  = qkv + 3 * NX;          // 16 MB
    u16* sb  = vt + NX;               // 33.5 MB scores/probs (bf16, in-place)

    cvt_bf16<<<NX / 8 / 256, 256, 0, stream>>>(x, xb);
    cvt_bf16<<<NWT / 8 / 256, 256, 0, stream>>>(wq, wb);
    cvt_bf16<<<NWT / 8 / 256, 256, 0, stream>>>(wk, wb + NWT);
    cvt_bf16<<<NWT / 8 / 256, 256, 0, stream>>>(wv, wb + 2 * NWT);

    qkv_gemm<<<dim3(64, 8, 3), 256, 0, stream>>>(xb, wb, qkv);

    vtrans<<<dim3(SEQ / 64, DOUT / 64, BATCH), 256, 0, stream>>>(qkv + 2 * NX, vt);

    qk_gemm<<<dim3(16, 16, 4), 256, 0, stream>>>(qkv, qkv + NX, sb);

    softmax_rows<<<(BATCH * SEQ) / 4, 256, 0, stream>>>(sb);

    pv_gemm<<<dim3(16, 8, 4), 256, 0, stream>>>(sb, vt, out);
}

// Round 3
// 200.454 us; speedup vs baseline: 2.0384x; 1.0541x over previous
//
#include <hip/hip_runtime.h>
#include <hip/hip_bf16.h>
#include <cstdint>

#define BATCH 4
#define SEQ   2048
#define DIN   1024
#define DOUT  1024
#define SCALE 0.03125f   // 1/sqrt(1024)

typedef unsigned short u16;
typedef float  f32x4  __attribute__((ext_vector_type(4)));
typedef __bf16 bf16x8 __attribute__((ext_vector_type(8)));

__device__ __forceinline__ u16 f2bf(float f) {
    unsigned u = __float_as_uint(f);
    unsigned r = 0x7fffu + ((u >> 16) & 1u);
    return (u16)((u + r) >> 16);
}

__device__ __forceinline__ f32x4 mfma16(bf16x8 a, bf16x8 b, f32x4 c) {
    return __builtin_amdgcn_mfma_f32_16x16x32_bf16(a, b, c, 0, 0, 0);
}

// async global->LDS, 16B per lane, wave-uniform LDS base
__device__ __forceinline__ void gl_lds16(const u16* g, u16* l) {
    __builtin_amdgcn_global_load_lds(
        (const __attribute__((address_space(1))) unsigned int*)g,
        (__attribute__((address_space(3))) unsigned int*)l, 16, 0, 0);
}

// st_16x32 XOR swizzle within 16KiB region (bit5 ^= bit9) — involution
#define SWZ(p) ((p) ^ ((((p) >> 9) & 1) << 5))

// ---------------- fp32 -> bf16 conversion (8 elems/thread) ----------------
__global__ __launch_bounds__(256) void cvt_bf16(const float* __restrict__ in,
                                                u16* __restrict__ out) {
    size_t i = ((size_t)blockIdx.x * 256 + threadIdx.x) * 8;
    f32x4 a = *(const f32x4*)(in + i);
    f32x4 b = *(const f32x4*)(in + i + 4);
    uint4 o;
    o.x = (unsigned)f2bf(a[0]) | ((unsigned)f2bf(a[1]) << 16);
    o.y = (unsigned)f2bf(a[2]) | ((unsigned)f2bf(a[3]) << 16);
    o.z = (unsigned)f2bf(b[0]) | ((unsigned)f2bf(b[1]) << 16);
    o.w = (unsigned)f2bf(b[2]) | ((unsigned)f2bf(b[3]) << 16);
    *(uint4*)(out + i) = o;
}

// ======================================================================
// Fused QKV GEMM: C[8192,3072] = X[8192,1024] * Wcat[3072,1024]^T
// 256x256 tile, BK=64, 8 waves (2Mx4N), 8-phase (4 phases/K-tile x dbuf),
// T2 st_16x32 swizzle (pre-swizzled global src, linear gl_lds dest),
// T4 counted vmcnt(4), T5 setprio around MFMA clusters.
// LDS 128KiB: A: buf*32768 + h*16384 ; B: 65536 + buf*32768 + h*16384
// A region h holds rows {h*64..h*64+63} U {128+h*64..+63} (qm-aligned)
// B region h holds rows with bit5==h: {wn*64 + h*32 .. +31} for wn=0..3
// ======================================================================
__device__ __forceinline__ void stageA8(const u16* __restrict__ xb, int m0, int k0,
                                        int h, u16* ldsreg, int tid) {
    const int w = tid >> 6;
#pragma unroll
    for (int i = 0; i < 2; i++) {
        int p = (i * 512 + tid) * 16;
        int o = SWZ(p);
        int lr = o >> 7, cb = o & 127;
        int grow = m0 + ((lr >> 6) << 7) + h * 64 + (lr & 63);
        gl_lds16(xb + (size_t)grow * DIN + k0 + (cb >> 1),
                 ldsreg + (i * 512 + w * 64) * 8);
    }
}

__device__ __forceinline__ void stageB8(const u16* __restrict__ wb, int n0, int k0,
                                        int h, u16* ldsreg, int tid) {
    const int w = tid >> 6;
#pragma unroll
    for (int i = 0; i < 2; i++) {
        int p = (i * 512 + tid) * 16;
        int o = SWZ(p);
        int lr = o >> 7, cb = o & 127;
        int grow = n0 + ((lr >> 5) << 6) + h * 32 + (lr & 31);
        gl_lds16(wb + (size_t)grow * DIN + k0 + (cb >> 1),
                 ldsreg + (i * 512 + w * 64) * 8);
    }
}

__global__ __launch_bounds__(512, 2) void qkv8p(const u16* __restrict__ xb,
                                                const u16* __restrict__ wb,
                                                u16* __restrict__ qkv) {
    extern __shared__ __align__(16) u16 lds[];
    const int bid = blockIdx.x;
    const int wg = (bid & 7) * 48 + (bid >> 3);   // bijective XCD swizzle (384%8==0)
    const int mt = wg & 31, nt = wg >> 5;         // mt fastest: W panel L2-resident/XCD
    const int m0 = mt * 256, n0 = nt * 256;
    const int tid = threadIdx.x, lane = tid & 63, wid = tid >> 6;
    const int wm = wid >> 2, wn = wid & 3;
    const int l15 = lane & 15, l4 = lane >> 4;
    const int nkt = DIN / 64;  // 16

    u16* ldsA[2][2], *ldsB[2][2];
#pragma unroll
    for (int b = 0; b < 2; b++)
#pragma unroll
        for (int h = 0; h < 2; h++) {
            ldsA[b][h] = lds + b * 16384 + h * 8192;
            ldsB[b][h] = lds + 32768 + b * 16384 + h * 8192;
        }

    f32x4 acc[2][2][4][2] = {};
    bf16x8 afr[4][2], bfr[2][2][2];

    // prologue: t0 all four halves, then t1.A0, t1.B0
    stageA8(xb, m0, 0, 0, ldsA[0][0], tid);
    stageB8(wb, n0, 0, 0, ldsB[0][0], tid);
    stageA8(xb, m0, 0, 1, ldsA[0][1], tid);
    stageB8(wb, n0, 0, 1, ldsB[0][1], tid);
    stageA8(xb, m0, 64, 0, ldsA[1][0], tid);
    stageB8(wb, n0, 64, 0, ldsB[1][0], tid);
    asm volatile("s_waitcnt vmcnt(4)" ::: "memory");  // t0 complete, t1 halves in flight
    asm volatile("s_barrier" ::: "memory");

    for (int t = 0; t < nkt; t++) {
        const int cur = t & 1, nxt = cur ^ 1;
        const int t1 = (t + 1 < nkt) ? t + 1 : nkt - 1;   // clamped (redundant at tail,
        const int t2 = (t + 2 < nkt) ? t + 2 : nkt - 1;   // keeps vmcnt accounting uniform)
#pragma unroll
        for (int ph = 0; ph < 4; ph++) {
            const int qm = ph >> 1, qn = ph & 1;
            const char* Ab = (const char*)lds + cur * 32768 + qm * 16384;
            const char* Bb = (const char*)lds + 65536 + cur * 32768 + qn * 16384;
            // ---- ds_reads for THIS phase's MFMA ----
            if (ph == 0 || ph == 2) {
#pragma unroll
                for (int mi = 0; mi < 4; mi++)
#pragma unroll
                    for (int kk = 0; kk < 2; kk++)
                        afr[mi][kk] = *(const bf16x8*)(Ab +
                            SWZ((wm * 64 + mi * 16 + l15) * 128 + kk * 64 + l4 * 16));
            }
            if (ph == 0 || ph == 1) {
#pragma unroll
                for (int ni = 0; ni < 2; ni++)
#pragma unroll
                    for (int kk = 0; kk < 2; kk++)
                        bfr[qn][ni][kk] = *(const bf16x8*)(Bb +
                            SWZ((wn * 32 + ni * 16 + l15) * 128 + kk * 64 + l4 * 16));
            }
            // ---- stage one half-tile (phase-disjoint from all readers) ----
            if (ph == 0) stageA8(xb, m0, t1 * 64, 1, ldsA[nxt][1], tid);
            if (ph == 1) stageB8(wb, n0, t1 * 64, 1, ldsB[nxt][1], tid);
            if (ph == 2) stageA8(xb, m0, t2 * 64, 0, ldsA[cur][0], tid);
            if (ph == 3) {
                stageB8(wb, n0, t2 * 64, 0, ldsB[cur][0], tid);
                asm volatile("s_waitcnt vmcnt(4)" ::: "memory");  // next tile ready
            }
            asm volatile("s_barrier" ::: "memory");
            __builtin_amdgcn_s_setprio(1);
#pragma unroll
            for (int kk = 0; kk < 2; kk++)
#pragma unroll
                for (int mi = 0; mi < 4; mi++)
#pragma unroll
                    for (int ni = 0; ni < 2; ni++)
                        acc[qm][qn][mi][ni] =
                            mfma16(afr[mi][kk], bfr[qn][ni][kk], acc[qm][qn][mi][ni]);
            __builtin_amdgcn_s_setprio(0);
            asm volatile("s_barrier" ::: "memory");
        }
    }
    asm volatile("s_waitcnt vmcnt(0)" ::: "memory");  // drain tail garbage stages

    const int wsel = n0 >> 10;
    u16* Op = qkv + (size_t)wsel * ((size_t)BATCH * SEQ * DOUT);
    const int c0 = n0 & 1023;
#pragma unroll
    for (int qm = 0; qm < 2; qm++)
#pragma unroll
        for (int qn = 0; qn < 2; qn++)
#pragma unroll
            for (int mi = 0; mi < 4; mi++)
#pragma unroll
                for (int ni = 0; ni < 2; ni++)
#pragma unroll
                    for (int rr = 0; rr < 4; rr++) {
                        int row = m0 + wm * 128 + qm * 64 + mi * 16 + l4 * 4 + rr;
                        int col = c0 + wn * 64 + qn * 32 + ni * 16 + l15;
                        Op[(size_t)row * DOUT + col] = f2bf(acc[qm][qn][mi][ni][rr]);
                    }
}

// ---------------- m97-style pieces for qk/pv (unchanged) -------------------
__device__ __forceinline__ void stage_tile(const u16* __restrict__ g, int ldg,
                                           u16* lds, int tid) {
    const int wv = tid >> 6;
#pragma unroll
    for (int i = 0; i < 4; i++) {
        int e = (i * 256 + tid) * 8;
        int r = e >> 6, c = e & 63;
        gl_lds16(g + (size_t)r * ldg + c, lds + (size_t)(i * 256 + wv * 64) * 8);
    }
}

__device__ __forceinline__ void kstep(const u16* As, const u16* Bs,
                                      int wr, int wc, int l15, int l4,
                                      f32x4 acc[4][4]) {
#pragma unroll
    for (int kk = 0; kk < 2; kk++) {
        bf16x8 af[4], bfr[4];
#pragma unroll
        for (int mi = 0; mi < 4; mi++)
            af[mi] = *(const bf16x8*)&As[(wr + mi * 16 + l15) * 64 + kk * 32 + l4 * 8];
#pragma unroll
        for (int ni = 0; ni < 4; ni++)
            bfr[ni] = *(const bf16x8*)&Bs[(wc + ni * 16 + l15) * 64 + kk * 32 + l4 * 8];
#pragma unroll
        for (int mi = 0; mi < 4; mi++)
#pragma unroll
            for (int ni = 0; ni < 4; ni++)
                acc[mi][ni] = mfma16(af[mi], bfr[ni], acc[mi][ni]);
    }
}

// ---------------- V transpose: v[b][s][d] -> vt[b][d][s] -------------------
__global__ __launch_bounds__(256) void vtrans(const u16* __restrict__ v,
                                              u16* __restrict__ vt) {
    __shared__ __align__(16) u16 t[64][80];
    const int s0 = blockIdx.x * 64, d0 = blockIdx.y * 64;
    const size_t bo = (size_t)blockIdx.z * SEQ * DOUT;
    const int tid = threadIdx.x;
#pragma unroll
    for (int i = 0; i < 2; i++) {
        int e = (tid + i * 256) * 8;
        int r = e >> 6, c = e & 63;
        *(uint4*)&t[r][c] = *(const uint4*)&v[bo + (size_t)(s0 + r) * DOUT + d0 + c];
    }
    __syncthreads();
#pragma unroll
    for (int i = 0; i < 2; i++) {
        int e = (tid + i * 256) * 8;
        int rd = e >> 6, cs = e & 63;
        u16 tmp[8];
#pragma unroll
        for (int j = 0; j < 8; j++) tmp[j] = t[cs + j][rd];
        uint4 o;
        o.x = (unsigned)tmp[0] | ((unsigned)tmp[1] << 16);
        o.y = (unsigned)tmp[2] | ((unsigned)tmp[3] << 16);
        o.z = (unsigned)tmp[4] | ((unsigned)tmp[5] << 16);
        o.w = (unsigned)tmp[6] | ((unsigned)tmp[7] << 16);
        *(uint4*)&vt[(size_t)blockIdx.z * DOUT * SEQ + (size_t)(d0 + rd) * SEQ + s0 + cs] = o;
    }
}

// ---------------- QK^T: S[b][q][k] (bf16, scaled+masked), causal skip ------
__global__ __launch_bounds__(256) void qk_gemm(const u16* __restrict__ qg,
                                               const u16* __restrict__ kg,
                                               u16* __restrict__ sg) {
    const int mt = blockIdx.x, nt = blockIdx.y, b = blockIdx.z;
    if (nt > mt) return;  // above diagonal: never read downstream
    __shared__ __align__(16) u16 As[128 * 64];
    __shared__ __align__(16) u16 Bs[128 * 64];
    const size_t bo = (size_t)b * SEQ * DOUT;
    const size_t so = (size_t)b * SEQ * SEQ;
    const int tid = threadIdx.x, lane = tid & 63, wv = tid >> 6;
    const int wr = (wv >> 1) * 64, wc = (wv & 1) * 64;
    const int l15 = lane & 15, l4 = lane >> 4;
    const int m0 = mt * 128, n0 = nt * 128;
    f32x4 acc[4][4] = {};

    for (int k0 = 0; k0 < DIN; k0 += 64) {
        __syncthreads();
        stage_tile(qg + bo + (size_t)m0 * DOUT + k0, DOUT, As, tid);
        stage_tile(kg + bo + (size_t)n0 * DOUT + k0, DOUT, Bs, tid);
        __syncthreads();
        kstep(As, Bs, wr, wc, l15, l4, acc);
    }
#pragma unroll
    for (int mi = 0; mi < 4; mi++)
#pragma unroll
        for (int rr = 0; rr < 4; rr++) {
            int q = m0 + wr + mi * 16 + l4 * 4 + rr;
#pragma unroll
            for (int ni = 0; ni < 4; ni++) {
                int kcol = n0 + wc + ni * 16 + l15;
                u16 val = (kcol <= q) ? f2bf(acc[mi][ni][rr] * SCALE) : (u16)0xFF80;
                sg[so + (size_t)q * SEQ + kcol] = val;
            }
        }
}

// ---------------- row softmax in place: one wave per row -------------------
__global__ __launch_bounds__(256) void softmax_rows(u16* __restrict__ sg) {
    const int row = blockIdx.x * 4 + (threadIdx.x >> 6);  // 0..8191
    const int lane = threadIdx.x & 63;
    const int b = row >> 11, q = row & 2047;
    u16* srow = sg + (size_t)b * SEQ * SEQ + (size_t)q * SEQ;
    const int kend = ((q >> 7) + 1) << 7;
    float v[4][8];
    float m = -__builtin_inff();
#pragma unroll
    for (int c = 0; c < 4; c++) {
        int k = c * 512 + lane * 8;
        if (k < kend) {
            uint4 x = *(const uint4*)&srow[k];
            unsigned w0 = x.x, w1 = x.y, w2 = x.z, w3 = x.w;
            v[c][0] = __uint_as_float(w0 << 16); v[c][1] = __uint_as_float(w0 & 0xffff0000u);
            v[c][2] = __uint_as_float(w1 << 16); v[c][3] = __uint_as_float(w1 & 0xffff0000u);
            v[c][4] = __uint_as_float(w2 << 16); v[c][5] = __uint_as_float(w2 & 0xffff0000u);
            v[c][6] = __uint_as_float(w3 << 16); v[c][7] = __uint_as_float(w3 & 0xffff0000u);
        } else {
#pragma unroll
            for (int j = 0; j < 8; j++) v[c][j] = -__builtin_inff();
        }
#pragma unroll
        for (int j = 0; j < 8; j++) m = fmaxf(m, v[c][j]);
    }
#pragma unroll
    for (int off = 32; off >= 1; off >>= 1) m = fmaxf(m, __shfl_xor(m, off));
    float s = 0.f;
#pragma unroll
    for (int c = 0; c < 4; c++)
#pragma unroll
        for (int j = 0; j < 8; j++) { v[c][j] = __expf(v[c][j] - m); s += v[c][j]; }
#pragma unroll
    for (int off = 32; off >= 1; off >>= 1) s += __shfl_xor(s, off);
    float inv = 1.f / s;
#pragma unroll
    for (int c = 0; c < 4; c++) {
        int k = c * 512 + lane * 8;
        if (k < kend) {
            uint4 o;
            o.x = (unsigned)f2bf(v[c][0] * inv) | ((unsigned)f2bf(v[c][1] * inv) << 16);
            o.y = (unsigned)f2bf(v[c][2] * inv) | ((unsigned)f2bf(v[c][3] * inv) << 16);
            o.z = (unsigned)f2bf(v[c][4] * inv) | ((unsigned)f2bf(v[c][5] * inv) << 16);
            o.w = (unsigned)f2bf(v[c][6] * inv) | ((unsigned)f2bf(v[c][7] * inv) << 16);
            *(uint4*)&srow[k] = o;
        }
    }
}

// ---------------- PV: O[b][q][d] = P * V, fp32 out, causal K-bound ---------
__global__ __launch_bounds__(256) void pv_gemm(const u16* __restrict__ pg,
                                               const u16* __restrict__ vtg,
                                               float* __restrict__ og) {
    __shared__ __align__(16) u16 As[128 * 64];
    __shared__ __align__(16) u16 Bs[128 * 64];
    const int mt = blockIdx.x, nt = blockIdx.y, b = blockIdx.z;
    const size_t so = (size_t)b * SEQ * SEQ;
    const size_t vo = (size_t)b * DOUT * SEQ;
    const size_t oo = (size_t)b * SEQ * DOUT;
    const int tid = threadIdx.x, lane = tid & 63, wv = tid >> 6;
    const int wr = (wv >> 1) * 64, wc = (wv & 1) * 64;
    const int l15 = lane & 15, l4 = lane >> 4;
    const int m0 = mt * 128, n0 = nt * 128;
    const int kend = (mt + 1) * 128;
    f32x4 acc[4][4] = {};

    for (int k0 = 0; k0 < kend; k0 += 64) {
        __syncthreads();
        stage_tile(pg + so + (size_t)m0 * SEQ + k0, SEQ, As, tid);
        stage_tile(vtg + vo + (size_t)n0 * SEQ + k0, SEQ, Bs, tid);
        __syncthreads();
        kstep(As, Bs, wr, wc, l15, l4, acc);
    }
#pragma unroll
    for (int mi = 0; mi < 4; mi++)
#pragma unroll
        for (int rr = 0; rr < 4; rr++) {
            int q = m0 + wr + mi * 16 + l4 * 4 + rr;
#pragma unroll
            for (int ni = 0; ni < 4; ni++) {
                int d = n0 + wc + ni * 16 + l15;
                og[oo + (size_t)q * DOUT + d] = acc[mi][ni][rr];
            }
        }
}

extern "C" void kernel_launch(void* const* d_in, const int* in_sizes, int n_in,
                              void* d_out, int out_size, void* d_ws, size_t ws_size,
                              hipStream_t stream) {
    const float* x  = (const float*)d_in[0];
    const float* wq = (const float*)d_in[1];
    const float* wk = (const float*)d_in[2];
    const float* wv = (const float*)d_in[3];
    float* out = (float*)d_out;

    const size_t NX  = (size_t)BATCH * SEQ * DIN;  // 8M elems
    const size_t NWT = (size_t)DOUT * DIN;         // 1M elems
    u16* xb  = (u16*)d_ws;            // 16 MB
    u16* wb  = xb + NX;               // 6 MB (wq|wk|wv contiguous = Wcat[3072][1024])
    u16* qkv = wb + 3 * NWT;          // 48 MB (q,k,v)
    u16* vt  = qkv + 3 * NX;          // 16 MB
    u16* sb  = vt + NX;               // 33.5 MB scores/probs (bf16, in-place)

    cvt_bf16<<<NX / 8 / 256, 256, 0, stream>>>(x, xb);
    cvt_bf16<<<NWT / 8 / 256, 256, 0, stream>>>(wq, wb);
    cvt_bf16<<<NWT / 8 / 256, 256, 0, stream>>>(wk, wb + NWT);
    cvt_bf16<<<NWT / 8 / 256, 256, 0, stream>>>(wv, wb + 2 * NWT);

    (void)hipFuncSetAttribute((const void*)qkv8p,
                              hipFuncAttributeMaxDynamicSharedMemorySize, 131072);
    qkv8p<<<dim3(384), dim3(512), 131072, stream>>>(xb, wb, qkv);

    vtrans<<<dim3(SEQ / 64, DOUT / 64, BATCH), 256, 0, stream>>>(qkv + 2 * NX, vt);

    qk_gemm<<<dim3(16, 16, 4), 256, 0, stream>>>(qkv, qkv + NX, sb);

    softmax_rows<<<(BATCH * SEQ) / 4, 256, 0, stream>>>(sb);

    pv_gemm<<<dim3(16, 8, 4), 256, 0, stream>>>(sb, vt, out);
}